// Round 4
// baseline (592.436 us; speedup 1.0000x reference)
//
#include <hip/hip_runtime.h>
#include <math.h>

// NCE loss: N=16384 rows x D=4096, fp32.
// out = mean_i( logsumexp(logits_i/alpha) - logits_i[argmax(labels_i)]/alpha )
// Streaming 512 MB (labels+logits); mask untouched. HBM floor ~81 us.
//
// R3 structure: wave-per-row; FULL logits row slice resident in registers
// (16 vf4/lane) -> plain (non-online) stable logsumexp with tree reductions,
// 64 exps/lane instead of 80 and no serial m/s dependency chain. Labels
// stream through a ping-pong 2x4-vf4 buffer so loads issue continuously.

typedef float vf4 __attribute__((ext_vector_type(4)));

constexpr int Dk    = 4096;
constexpr int BLOCK = 256;   // 4 waves = 4 rows per block
constexpr int RPB   = 4;

__global__ __launch_bounds__(BLOCK) void nce_main(
    const float* __restrict__ labels, const float* __restrict__ logits,
    const float* __restrict__ alpha, float* __restrict__ bins)
{
    const int lane = threadIdx.x & 63;
    const int row  = blockIdx.x * RPB + (threadIdx.x >> 6);
    const size_t base = (size_t)row * Dk;
    const vf4* g4 = reinterpret_cast<const vf4*>(logits + base);
    const vf4* l4 = reinterpret_cast<const vf4*>(labels + base);
    const float ia = 1.0f / alpha[0];

    // Entire logits slice for this lane: 16 x 16B NT loads, stays resident.
    vf4 g[16];
#pragma unroll
    for (int j = 0; j < 16; ++j)
        g[j] = __builtin_nontemporal_load(g4 + lane + 64 * j);

    // Labels ping-pong: chunks of 4 vf4; chunk c+1 in flight while c processes.
    vf4 lb[2][4];
#pragma unroll
    for (int j = 0; j < 4; ++j)
        lb[0][j] = __builtin_nontemporal_load(l4 + lane + 64 * j);
#pragma unroll
    for (int j = 0; j < 4; ++j)
        lb[1][j] = __builtin_nontemporal_load(l4 + lane + 64 * (4 + j));

    float lmax = -INFINITY, lval = 0.0f;
    int   lidx = 0x7fffffff;

#pragma unroll
    for (int c = 0; c < 4; ++c) {
        const int b = c & 1;
#pragma unroll
        for (int j = 0; j < 4; ++j) {
            const int jj = 4 * c + j;
#pragma unroll
            for (int e = 0; e < 4; ++e) {
                const float le  = lb[b][j][e];
                const int   idx = 4 * (lane + 64 * jj) + e;
                // first-occurrence argmax (tie -> smaller index) = jnp.argmax
                if (le > lmax || (le == lmax && idx < lidx)) {
                    lmax = le; lidx = idx; lval = g[jj][e];
                }
            }
        }
        if (c + 2 < 4) {
#pragma unroll
            for (int j = 0; j < 4; ++j)
                lb[b][j] = __builtin_nontemporal_load(l4 + lane + 64 * (4 * (c + 2) + j));
        }
    }

    // Lane max over resident logits: tree, no serial chain.
    float pm[16];
#pragma unroll
    for (int j = 0; j < 16; ++j)
        pm[j] = fmaxf(fmaxf(g[j][0], g[j][1]), fmaxf(g[j][2], g[j][3]));
#pragma unroll
    for (int off = 8; off; off >>= 1)
#pragma unroll
        for (int j = 0; j < 16; ++j)
            if (j < off) pm[j] = fmaxf(pm[j], pm[j + off]);
    float M = pm[0];
#pragma unroll
    for (int off = 1; off < 64; off <<= 1)
        M = fmaxf(M, __shfl_xor(M, off));

    // Plain stable exp-sum from registers, 4 independent accumulators.
    float s0 = 0.f, s1 = 0.f, s2 = 0.f, s3 = 0.f;
#pragma unroll
    for (int j = 0; j < 16; j += 4) {
        s0 += __expf((g[j+0][0] - M) * ia) + __expf((g[j+0][1] - M) * ia)
            + __expf((g[j+0][2] - M) * ia) + __expf((g[j+0][3] - M) * ia);
        s1 += __expf((g[j+1][0] - M) * ia) + __expf((g[j+1][1] - M) * ia)
            + __expf((g[j+1][2] - M) * ia) + __expf((g[j+1][3] - M) * ia);
        s2 += __expf((g[j+2][0] - M) * ia) + __expf((g[j+2][1] - M) * ia)
            + __expf((g[j+2][2] - M) * ia) + __expf((g[j+2][3] - M) * ia);
        s3 += __expf((g[j+3][0] - M) * ia) + __expf((g[j+3][1] - M) * ia)
            + __expf((g[j+3][2] - M) * ia) + __expf((g[j+3][3] - M) * ia);
    }
    float s = (s0 + s1) + (s2 + s3);

    // Wave reduce: sum + argmax triple (result lands in lane 0).
#pragma unroll
    for (int off = 32; off; off >>= 1) {
        s += __shfl_down(s, off);
        const float om = __shfl_down(lmax, off);
        const int   oi = __shfl_down(lidx, off);
        const float ov = __shfl_down(lval, off);
        if (om > lmax || (om == lmax && oi < lidx)) { lmax = om; lidx = oi; lval = ov; }
    }

    if (lane == 0)
        bins[row] = (M - lval) * ia + logf(s);
}

// Reduce 16384 per-row values -> mean. One block.
__global__ __launch_bounds__(BLOCK) void nce_finalize(
    const float* __restrict__ bins, float* __restrict__ out, int n, float inv_n)
{
    const int t = threadIdx.x;
    float v = 0.0f;
    for (int i = t; i < n; i += BLOCK) v += bins[i];
#pragma unroll
    for (int off = 32; off; off >>= 1) v += __shfl_down(v, off);
    __shared__ float s_w[BLOCK / 64];
    if ((t & 63) == 0) s_w[t >> 6] = v;
    __syncthreads();
    if (t == 0) out[0] = (s_w[0] + s_w[1] + s_w[2] + s_w[3]) * inv_n;
}

extern "C" void kernel_launch(void* const* d_in, const int* in_sizes, int n_in,
                              void* d_out, int out_size, void* d_ws, size_t ws_size,
                              hipStream_t stream) {
    const float* labels = (const float*)d_in[0];
    const float* logits = (const float*)d_in[1];
    // d_in[2] = mask (unused by the reference math)
    const float* alpha  = (const float*)d_in[3];
    float* out  = (float*)d_out;
    float* bins = (float*)d_ws;   // N floats = 64 KB scratch

    const int N = in_sizes[0] / Dk;  // 16384

    nce_main<<<N / RPB, BLOCK, 0, stream>>>(labels, logits, alpha, bins);
    nce_finalize<<<1, BLOCK, 0, stream>>>(bins, out, N, 1.0f / (float)N);
}